// Round 5
// baseline (863.246 us; speedup 1.0000x reference)
//
#include <hip/hip_runtime.h>
#include <hip/hip_bf16.h>
#include <math.h>

#define N_NODES 50000
#define M_PAD   50048           // 782 blocks * 64 rows
#define E_EDGES 800000
#define IN_DIM  512
#define HDIM    128
#define CDIM    40
#define LAYERS  8

typedef __attribute__((ext_vector_type(8))) short short8;
typedef __attribute__((ext_vector_type(4))) short short4v;
typedef __attribute__((ext_vector_type(4))) float floatx4;
typedef unsigned short ushort_t;

__device__ inline float bf2f(unsigned short u) {
    return __uint_as_float(((unsigned)u) << 16);
}
__device__ inline unsigned short f2bf(float v) {
    __hip_bfloat16 b = __float2bfloat16(v);
    return *reinterpret_cast<unsigned short*>(&b);
}

// ---------------- CSR build ----------------

__global__ void hist_kernel(const int* __restrict__ dst, int* __restrict__ cnt) {
    int i = blockIdx.x * blockDim.x + threadIdx.x;
    if (i < E_EDGES) atomicAdd(&cnt[dst[i]], 1);
}

__global__ void scan_kernel(const int* __restrict__ cnt, int* __restrict__ row_start) {
    __shared__ int partial[1024];
    const int n = N_NODES;
    int t = threadIdx.x;
    int chunk = (n + 1023) >> 10;
    int lo = t * chunk;
    int hi = lo + chunk; if (hi > n) hi = n;
    int s = 0;
    for (int i = lo; i < hi; i++) s += cnt[i];
    partial[t] = s;
    __syncthreads();
    for (int d = 1; d < 1024; d <<= 1) {
        int v = (t >= d) ? partial[t - d] : 0;
        __syncthreads();
        partial[t] += v;
        __syncthreads();
    }
    int base = (t > 0) ? partial[t - 1] : 0;
    for (int i = lo; i < hi; i++) { row_start[i] = base; base += cnt[i]; }
    if (t == 1023) row_start[n] = partial[1023];
}

__global__ void scatter_kernel(const int* __restrict__ ei, const float* __restrict__ normA,
                               int* __restrict__ cursor, int2* __restrict__ perm) {
    int i = blockIdx.x * blockDim.x + threadIdx.x;
    if (i >= E_EDGES) return;
    int d = ei[E_EDGES + i];
    int idx = atomicAdd(&cursor[d], 1);
    perm[idx] = make_int2(ei[i], __float_as_int(normA[i]));
}

// ---------------- weight prep: transpose + bf16 convert ----------------

__global__ void prep_weights(const float* __restrict__ W0, const float* __restrict__ convW,
                             const float* __restrict__ W1,
                             ushort_t* __restrict__ Wt0, ushort_t* __restrict__ WtL,
                             ushort_t* __restrict__ Wt1) {
    int i = blockIdx.x * blockDim.x + threadIdx.x;
    if (i < 128 * 512) {
        int n = i >> 9, k = i & 511;
        Wt0[i] = f2bf(W0[k * HDIM + n]);
        return;
    }
    int j = i - 128 * 512;
    if (j < 8 * 128 * 128) {
        int l = j >> 14, rem = j & 16383, n = rem >> 7, k = rem & 127;
        WtL[j] = f2bf(convW[l * 16384 + k * HDIM + n]);
        return;
    }
    int m = j - 8 * 128 * 128;
    if (m < 48 * 128) {
        int n = m >> 7, k = m & 127;
        Wt1[m] = (n < CDIM) ? f2bf(W1[k * CDIM + n]) : (ushort_t)0;
    }
}

// ---------------- fc0: x = relu(F @ W0 + b0) -> h0b, xab (bf16) ----------------
// 512 thr (8 waves): 64 rows x 128 cols; wave = 16 rows x 64 cols (rg 0..3, cg 0..1)
// K=512 in 4 LDS chunks of 128, register-prefetch pipeline on the staging loads

#define SROW 136   // 128 + 8 pad

__global__ void fc0_mfma(const float* __restrict__ F, const ushort_t* __restrict__ Wt0,
                         const float* __restrict__ b0,
                         ushort_t* __restrict__ h0b, ushort_t* __restrict__ xab) {
    __shared__ short sA[64][SROW];   // 17.4 KB
    int t = threadIdx.x;
    int wave = t >> 6, lane = t & 63;
    int quad = lane >> 4, l16 = lane & 15;
    int rg = wave >> 1, cg = wave & 1;
    int row0 = blockIdx.x * 64;

    int r0 = t >> 5;           // 0..15
    int c4 = (t & 31) * 4;     // 0..124

    // clamp the 4 staging rows once
    int frow[4];
#pragma unroll
    for (int j = 0; j < 4; j++) {
        int fr = row0 + r0 + 16 * j;
        frow[j] = fr > N_NODES - 1 ? N_NODES - 1 : fr;
    }

    floatx4 acc[4];
#pragma unroll
    for (int nt = 0; nt < 4; nt++) acc[nt] = (floatx4){0.f, 0.f, 0.f, 0.f};

    float4 pf[4];
    // prefetch chunk 0
#pragma unroll
    for (int j = 0; j < 4; j++)
        pf[j] = *(const float4*)(F + (size_t)frow[j] * IN_DIM + c4);

    for (int kc = 0; kc < 4; kc++) {
        // convert prefetched regs -> LDS
#pragma unroll
        for (int j = 0; j < 4; j++) {
            short4v s;
            s[0] = (short)f2bf(pf[j].x); s[1] = (short)f2bf(pf[j].y);
            s[2] = (short)f2bf(pf[j].z); s[3] = (short)f2bf(pf[j].w);
            *(short4v*)&sA[r0 + 16 * j][c4] = s;
        }
        __syncthreads();
        // issue next chunk's loads; they drain during the MFMA phase + barrier
        if (kc < 3) {
#pragma unroll
            for (int j = 0; j < 4; j++)
                pf[j] = *(const float4*)(F + (size_t)frow[j] * IN_DIM + (kc + 1) * 128 + c4);
        }
#pragma unroll
        for (int ks = 0; ks < 4; ks++) {
            short8 a = *(const short8*)&sA[rg * 16 + l16][ks * 32 + quad * 8];
#pragma unroll
            for (int nt = 0; nt < 4; nt++) {
                short8 b = *(const short8*)(Wt0 + (size_t)(cg * 64 + nt * 16 + l16) * IN_DIM +
                                            kc * 128 + ks * 32 + quad * 8);
                acc[nt] = __builtin_amdgcn_mfma_f32_16x16x32_bf16(a, b, acc[nt], 0, 0, 0);
            }
        }
        __syncthreads();
    }
#pragma unroll
    for (int nt = 0; nt < 4; nt++) {
        int col = cg * 64 + nt * 16 + l16;
        float bias = b0[col];
#pragma unroll
        for (int r = 0; r < 4; r++) {
            int row = row0 + rg * 16 + quad * 4 + r;
            float v = acc[nt][r] + bias;
            v = v > 0.f ? v : 0.f;
            ushort_t u = f2bf(v);
            h0b[(size_t)row * HDIM + col] = u;
            xab[(size_t)row * HDIM + col] = u;
        }
    }
}

// ---------------- SpMM + mix: sup = 0.9*(A x) + 0.1*h0 (bf16 in/out) ----------------
// wave = 1 dst row; 4 edge slots x 16 lanes; 2-deep gather pipeline per slot

__global__ void spmm_kernel(const int* __restrict__ row_start,
                            const int2* __restrict__ perm,
                            const ushort_t* __restrict__ xb,
                            const ushort_t* __restrict__ h0b,
                            ushort_t* __restrict__ supb) {
    int row  = blockIdx.x * 4 + (threadIdx.x >> 6);
    int lane = threadIdx.x & 63;
    int slot = lane >> 4, sl = lane & 15;
    if (row >= N_NODES) return;
    int e0 = row_start[row], e1 = row_start[row + 1];

    float acc[8];
#pragma unroll
    for (int c = 0; c < 8; c++) acc[c] = 0.f;

    int eA = e0 + slot;                    // this slot: eA, eA+4, eA+8, ...
    int2 mA = make_int2(0, 0), mB = make_int2(0, 0);
    if (eA < e1)     mA = perm[eA];
    if (eA + 4 < e1) mB = perm[eA + 4];
    short8 vA, vB;
#pragma unroll
    for (int c = 0; c < 8; c++) { vA[c] = 0; vB[c] = 0; }
    if (eA < e1) vA = *(const short8*)(xb + (size_t)mA.x * HDIM + sl * 8);

    for (int e = eA; e < e1; e += 8) {
        if (e + 4 < e1) vB = *(const short8*)(xb + (size_t)mB.x * HDIM + sl * 8);
        int2 mA2 = make_int2(0, 0), mB2 = make_int2(0, 0);
        if (e + 8  < e1) mA2 = perm[e + 8];
        if (e + 12 < e1) mB2 = perm[e + 12];
        // consume A (vB + next metas stay in flight)
        float wA = __int_as_float(mA.y);
#pragma unroll
        for (int c = 0; c < 8; c++) acc[c] += wA * bf2f((ushort_t)vA[c]);
        // issue next A gather before consuming B
        if (e + 8 < e1) vA = *(const short8*)(xb + (size_t)mA2.x * HDIM + sl * 8);
        if (e + 4 < e1) {
            float wB = __int_as_float(mB.y);
#pragma unroll
            for (int c = 0; c < 8; c++) acc[c] += wB * bf2f((ushort_t)vB[c]);
        }
        mA = mA2; mB = mB2;
    }
    // reduce across the 4 slots
#pragma unroll
    for (int c = 0; c < 8; c++) {
        acc[c] += __shfl_xor(acc[c], 16);
        acc[c] += __shfl_xor(acc[c], 32);
    }
    if (slot == 0) {
        short8 h = *(const short8*)(h0b + (size_t)row * HDIM + sl * 8);
        short8 o;
#pragma unroll
        for (int c = 0; c < 8; c++)
            o[c] = (short)f2bf(0.9f * acc[c] + 0.1f * bf2f((ushort_t)h[c]));
        *(short8*)(supb + (size_t)row * HDIM + sl * 8) = o;
    }
}

// ---------- layer GEMM: x = relu(beta*(S@W) + (1-beta)*S), bf16 in/out ----------

__global__ void layer_gemm_mfma(const ushort_t* __restrict__ S, const ushort_t* __restrict__ Wt,
                                ushort_t* __restrict__ X, float beta) {
    __shared__ short sS[64][SROW];   // 17.4 KB
    int t = threadIdx.x;
    int wave = t >> 6, lane = t & 63;
    int quad = lane >> 4, l16 = lane & 15;
    int row0 = blockIdx.x * 64;

#pragma unroll
    for (int i = 0; i < 4; i++) {
        int idx = t + i * 256;
        int r = idx >> 4, c8 = (idx & 15) * 8;
        *(short8*)&sS[r][c8] = *(const short8*)(S + (size_t)(row0 + r) * HDIM + c8);
    }
    __syncthreads();

    short8 afrag[4];
#pragma unroll
    for (int ks = 0; ks < 4; ks++)
        afrag[ks] = *(const short8*)&sS[wave * 16 + l16][ks * 32 + quad * 8];

    floatx4 acc[8];
#pragma unroll
    for (int nt = 0; nt < 8; nt++) {
        const ushort_t* bp = Wt + (size_t)(nt * 16 + l16) * HDIM + quad * 8;
        floatx4 c = (floatx4){0.f, 0.f, 0.f, 0.f};
#pragma unroll
        for (int ks = 0; ks < 4; ks++) {
            short8 b = *(const short8*)(bp + ks * 32);
            c = __builtin_amdgcn_mfma_f32_16x16x32_bf16(afrag[ks], b, c, 0, 0, 0);
        }
        acc[nt] = c;
    }
    float g = 1.f - beta;
#pragma unroll
    for (int nt = 0; nt < 8; nt++) {
        int col = nt * 16 + l16;
#pragma unroll
        for (int r = 0; r < 4; r++) {
            int lrow = wave * 16 + quad * 4 + r;
            float s = bf2f((ushort_t)sS[lrow][col]);
            float v = beta * acc[nt][r] + g * s;
            v = v > 0.f ? v : 0.f;
            X[(size_t)(row0 + lrow) * HDIM + col] = f2bf(v);
        }
    }
}

// ---------------- fc1: out = x @ W1 + b1 (fp32 out), N padded 40->48 ----------------

__global__ void fc1_mfma(const ushort_t* __restrict__ X, const ushort_t* __restrict__ Wt1,
                         const float* __restrict__ b1, float* __restrict__ out) {
    int wave = threadIdx.x >> 6;
    int lane = threadIdx.x & 63;
    int quad = lane >> 4, l16 = lane & 15;
    int row0 = blockIdx.x * 64 + wave * 16;

    int arow = row0 + l16; if (arow > N_NODES - 1) arow = N_NODES - 1;
    const ushort_t* ap = X + (size_t)arow * HDIM + quad * 8;
    short8 afrag[4];
#pragma unroll
    for (int ks = 0; ks < 4; ks++) afrag[ks] = *(const short8*)(ap + ks * 32);

    floatx4 acc[3];
#pragma unroll
    for (int nt = 0; nt < 3; nt++) {
        const ushort_t* bp = Wt1 + (size_t)(nt * 16 + l16) * HDIM + quad * 8;
        floatx4 c = (floatx4){0.f, 0.f, 0.f, 0.f};
#pragma unroll
        for (int ks = 0; ks < 4; ks++) {
            short8 b = *(const short8*)(bp + ks * 32);
            c = __builtin_amdgcn_mfma_f32_16x16x32_bf16(afrag[ks], b, c, 0, 0, 0);
        }
        acc[nt] = c;
    }
#pragma unroll
    for (int nt = 0; nt < 3; nt++) {
        int col = nt * 16 + l16;
        if (col < CDIM) {
            float bias = b1[col];
#pragma unroll
            for (int r = 0; r < 4; r++) {
                int row = row0 + quad * 4 + r;
                if (row < N_NODES)
                    out[(size_t)row * CDIM + col] = acc[nt][r] + bias;
            }
        }
    }
}

// ---------------- launch ----------------

extern "C" void kernel_launch(void* const* d_in, const int* in_sizes, int n_in,
                              void* d_out, int out_size, void* d_ws, size_t ws_size,
                              hipStream_t stream) {
    const float* F     = (const float*)d_in[0];
    const int*   ei    = (const int*)d_in[1];
    const float* normA = (const float*)d_in[2];
    const float* W0    = (const float*)d_in[3];
    const float* b0    = (const float*)d_in[4];
    const float* convW = (const float*)d_in[5];
    const float* W1    = (const float*)d_in[6];
    const float* b1    = (const float*)d_in[7];
    float*       out   = (float*)d_out;

    // workspace layout (bf16 trunk), 16B-aligned
    ushort_t* h0b  = (ushort_t*)d_ws;                     // M_PAD*128
    ushort_t* xab  = h0b + (size_t)M_PAD * HDIM;
    ushort_t* xbb  = xab + (size_t)M_PAD * HDIM;
    ushort_t* Wt0  = xbb + (size_t)M_PAD * HDIM;          // 128*512
    ushort_t* WtL  = Wt0 + 128 * 512;                     // 8*128*128
    ushort_t* Wt1  = WtL + 8 * 128 * 128;                 // 48*128
    int*   row_start = (int*)(Wt1 + 48 * 128);
    int*   cursor    = row_start + (N_NODES + 8);
    int2*  perm      = (int2*)(cursor + (N_NODES + 8));   // 8B-aligned

    // CSR build
    hipMemsetAsync(cursor, 0, N_NODES * sizeof(int), stream);
    hist_kernel<<<(E_EDGES + 255) / 256, 256, 0, stream>>>(ei + E_EDGES, cursor);
    scan_kernel<<<1, 1024, 0, stream>>>(cursor, row_start);
    hipMemcpyAsync(cursor, row_start, N_NODES * sizeof(int),
                   hipMemcpyDeviceToDevice, stream);
    scatter_kernel<<<(E_EDGES + 255) / 256, 256, 0, stream>>>(ei, normA, cursor, perm);
    prep_weights<<<(128 * 512 + 8 * 128 * 128 + 48 * 128 + 255) / 256, 256, 0, stream>>>(
        W0, convW, W1, Wt0, WtL, Wt1);

    fc0_mfma<<<M_PAD / 64, 512, 0, stream>>>(F, Wt0, b0, h0b, xab);

    for (int i = 0; i < LAYERS; i++) {
        float beta = logf(0.5f / (float)(i + 1) + 1.0f);
        spmm_kernel<<<(N_NODES + 3) / 4, 256, 0, stream>>>(
            row_start, perm, xab, h0b, xbb);
        layer_gemm_mfma<<<M_PAD / 64, 256, 0, stream>>>(
            xbb, WtL + (size_t)i * HDIM * HDIM, xab, beta);
    }

    fc1_mfma<<<M_PAD / 64, 256, 0, stream>>>(xab, Wt1, b1, out);
}

// Round 6
// 812.858 us; speedup vs baseline: 1.0620x; 1.0620x over previous
//
#include <hip/hip_runtime.h>
#include <hip/hip_bf16.h>
#include <math.h>

#define N_NODES 50000
#define M_PAD   50048           // 782 blocks * 64 rows
#define E_EDGES 800000
#define IN_DIM  512
#define HDIM    128
#define CDIM    40
#define LAYERS  8
#define NB      196             // scan blocks: ceil(50000/256)

typedef __attribute__((ext_vector_type(8))) short short8;
typedef __attribute__((ext_vector_type(4))) short short4v;
typedef __attribute__((ext_vector_type(4))) float floatx4;
typedef unsigned short ushort_t;

__device__ inline float bf2f(unsigned short u) {
    return __uint_as_float(((unsigned)u) << 16);
}
__device__ inline unsigned short f2bf(float v) {
    __hip_bfloat16 b = __float2bfloat16(v);
    return *reinterpret_cast<unsigned short*>(&b);
}

// ---------------- CSR build ----------------

__global__ void hist_kernel(const int* __restrict__ dst, int* __restrict__ cnt) {
    int i = blockIdx.x * blockDim.x + threadIdx.x;
    if (i < E_EDGES) atomicAdd(&cnt[dst[i]], 1);
}

__global__ void scanA(const int* __restrict__ cnt, int* __restrict__ bsum) {
    __shared__ int sm[256];
    int t = threadIdx.x, i = blockIdx.x * 256 + t;
    sm[t] = (i < N_NODES) ? cnt[i] : 0;
    __syncthreads();
    for (int d = 128; d > 0; d >>= 1) {
        if (t < d) sm[t] += sm[t + d];
        __syncthreads();
    }
    if (t == 0) bsum[blockIdx.x] = sm[0];
}

__global__ void scanB(const int* __restrict__ bsum, int* __restrict__ boff) {
    __shared__ int sm[256];
    int t = threadIdx.x;
    sm[t] = (t < NB) ? bsum[t] : 0;
    __syncthreads();
    for (int d = 1; d < 256; d <<= 1) {
        int v = (t >= d) ? sm[t - d] : 0;
        __syncthreads();
        sm[t] += v;
        __syncthreads();
    }
    if (t < NB) boff[t] = (t > 0) ? sm[t - 1] : 0;
}

__global__ void scanC(const int* __restrict__ cnt, const int* __restrict__ boff,
                      int* __restrict__ row_start, int* __restrict__ cursor) {
    __shared__ int sm[256];
    int t = threadIdx.x, i = blockIdx.x * 256 + t;
    int v = (i < N_NODES) ? cnt[i] : 0;
    sm[t] = v;
    __syncthreads();
    for (int d = 1; d < 256; d <<= 1) {
        int x = (t >= d) ? sm[t - d] : 0;
        __syncthreads();
        sm[t] += x;
        __syncthreads();
    }
    if (i < N_NODES) {
        int incl = boff[blockIdx.x] + sm[t];
        int excl = incl - v;
        row_start[i] = excl;
        cursor[i]    = excl;
        if (i == N_NODES - 1) row_start[N_NODES] = incl;
    }
}

__global__ void scatter_kernel(const int* __restrict__ ei, const float* __restrict__ normA,
                               int* __restrict__ cursor, int2* __restrict__ perm) {
    int i = blockIdx.x * blockDim.x + threadIdx.x;
    if (i >= E_EDGES) return;
    int d = ei[E_EDGES + i];
    int idx = atomicAdd(&cursor[d], 1);
    perm[idx] = make_int2(ei[i], __float_as_int(normA[i]));
}

// ---------------- weight prep: transpose + bf16 convert ----------------

__global__ void prep_weights(const float* __restrict__ W0, const float* __restrict__ convW,
                             const float* __restrict__ W1,
                             ushort_t* __restrict__ Wt0, ushort_t* __restrict__ WtL,
                             ushort_t* __restrict__ Wt1) {
    int i = blockIdx.x * blockDim.x + threadIdx.x;
    if (i < 128 * 512) {
        int n = i >> 9, k = i & 511;
        Wt0[i] = f2bf(W0[k * HDIM + n]);
        return;
    }
    int j = i - 128 * 512;
    if (j < 8 * 128 * 128) {
        int l = j >> 14, rem = j & 16383, n = rem >> 7, k = rem & 127;
        WtL[j] = f2bf(convW[l * 16384 + k * HDIM + n]);
        return;
    }
    int m = j - 8 * 128 * 128;
    if (m < 48 * 128) {
        int n = m >> 7, k = m & 127;
        Wt1[m] = (n < CDIM) ? f2bf(W1[k * CDIM + n]) : (ushort_t)0;
    }
}

// ---------------- fc0: x = relu(F @ W0 + b0) -> h0b, xab (bf16) ----------------
// 512 thr / 8 waves, 64 rows x 128 cols. Whole 64x512 F tile register-prefetched
// (16 float4/thread, all in flight before any barrier), then LDS, then MFMA.

#define AROW 520   // 512 + 8 pad (shorts)

__global__ __launch_bounds__(512)
void fc0_mfma(const float* __restrict__ F, const ushort_t* __restrict__ Wt0,
              const float* __restrict__ b0,
              ushort_t* __restrict__ h0b, ushort_t* __restrict__ xab) {
    __shared__ short sA[64][AROW];   // 66.5 KB
    int t = threadIdx.x;
    int wave = t >> 6, lane = t & 63;
    int quad = lane >> 4, l16 = lane & 15;
    int rg = wave >> 1, cg = wave & 1;
    int row0 = blockIdx.x * 64;

    float4 pf[16];
#pragma unroll
    for (int i = 0; i < 16; i++) {
        int idx = t * 4 + i * 2048;            // 0..32764
        int r = row0 + (idx >> 9);
        if (r > N_NODES - 1) r = N_NODES - 1;  // OOB guard (values unused)
        pf[i] = *(const float4*)(F + (size_t)r * IN_DIM + (idx & 511));
    }
#pragma unroll
    for (int i = 0; i < 16; i++) {
        int idx = t * 4 + i * 2048;
        short4v s;
        s[0] = (short)f2bf(pf[i].x); s[1] = (short)f2bf(pf[i].y);
        s[2] = (short)f2bf(pf[i].z); s[3] = (short)f2bf(pf[i].w);
        *(short4v*)&sA[idx >> 9][idx & 511] = s;
    }
    __syncthreads();

    floatx4 acc[4];
#pragma unroll
    for (int nt = 0; nt < 4; nt++) acc[nt] = (floatx4){0.f, 0.f, 0.f, 0.f};

#pragma unroll
    for (int kc = 0; kc < 4; kc++) {
#pragma unroll
        for (int ks = 0; ks < 4; ks++) {
            short8 a = *(const short8*)&sA[rg * 16 + l16][kc * 128 + ks * 32 + quad * 8];
#pragma unroll
            for (int nt = 0; nt < 4; nt++) {
                short8 b = *(const short8*)(Wt0 + (size_t)(cg * 64 + nt * 16 + l16) * IN_DIM +
                                            kc * 128 + ks * 32 + quad * 8);
                acc[nt] = __builtin_amdgcn_mfma_f32_16x16x32_bf16(a, b, acc[nt], 0, 0, 0);
            }
        }
    }
#pragma unroll
    for (int nt = 0; nt < 4; nt++) {
        int col = cg * 64 + nt * 16 + l16;
        float bias = b0[col];
#pragma unroll
        for (int r = 0; r < 4; r++) {
            int row = row0 + rg * 16 + quad * 4 + r;
            float v = acc[nt][r] + bias;
            v = v > 0.f ? v : 0.f;
            ushort_t u = f2bf(v);
            h0b[(size_t)row * HDIM + col] = u;
            xab[(size_t)row * HDIM + col] = u;
        }
    }
}

// -------- fused layer: sup = 0.9*(A x)+0.1*h0 (into LDS); x' = relu(beta*(sup W)+(1-beta)*sup)
// block = 64 rows, 256 thr / 4 waves. spmm: wave = 16 rows, 4 slots x 16 lanes, 4-deep pipeline.

#define SROW 136   // 128 + 8 pad

__global__ void layer_fused(const int* __restrict__ row_start, const int2* __restrict__ perm,
                            const ushort_t* __restrict__ xb, const ushort_t* __restrict__ h0b,
                            const ushort_t* __restrict__ Wt, ushort_t* __restrict__ X,
                            float beta) {
    __shared__ short sS[64][SROW];   // 17.4 KB
    int t = threadIdx.x;
    int wave = t >> 6, lane = t & 63;
    int slot = lane >> 4, sl = lane & 15;
    int quad = slot, l16 = sl;       // aliases for gemm phase
    int row0 = blockIdx.x * 64;
    int R0 = row0 + wave * 16;

    // this wave's 17 row bounds via lane loads
    int rb = 0;
    if (lane <= 16) {
        int idx = R0 + lane;
        if (idx > N_NODES) idx = N_NODES;
        rb = row_start[idx];
    }

    // ---- spmm phase ----
    for (int r = 0; r < 16; r++) {
        int e0 = __shfl(rb, r), e1 = __shfl(rb, r + 1);
        int grow = R0 + r;
        float acc[8];
#pragma unroll
        for (int c = 0; c < 8; c++) acc[c] = 0.f;

        int ebase = e0 + slot;
        int2 m[4];
        short8 v[4];
#pragma unroll
        for (int d = 0; d < 4; d++) {
            int e = ebase + 4 * d;
            m[d] = (e < e1) ? perm[e] : make_int2(0, 0);
        }
#pragma unroll
        for (int d = 0; d < 4; d++) {
            int e = ebase + 4 * d;
            if (e < e1) v[d] = *(const short8*)(xb + (size_t)m[d].x * HDIM + sl * 8);
        }
        for (int e = ebase; e < e1; e += 16) {
            int2 mn[4];
#pragma unroll
            for (int d = 0; d < 4; d++) {
                int en = e + 16 + 4 * d;
                mn[d] = (en < e1) ? perm[en] : make_int2(0, 0);
            }
#pragma unroll
            for (int d = 0; d < 4; d++) {
                int ec = e + 4 * d;
                if (ec < e1) {
                    float w = __int_as_float(m[d].y);
#pragma unroll
                    for (int c = 0; c < 8; c++) acc[c] += w * bf2f((ushort_t)v[d][c]);
                }
            }
#pragma unroll
            for (int d = 0; d < 4; d++) {
                int en = e + 16 + 4 * d;
                if (en < e1) v[d] = *(const short8*)(xb + (size_t)mn[d].x * HDIM + sl * 8);
                m[d] = mn[d];
            }
        }
#pragma unroll
        for (int c = 0; c < 8; c++) {
            acc[c] += __shfl_xor(acc[c], 16);
            acc[c] += __shfl_xor(acc[c], 32);
        }
        if (slot == 0) {
            short8 o;
            if (grow < N_NODES) {
                short8 h = *(const short8*)(h0b + (size_t)grow * HDIM + sl * 8);
#pragma unroll
                for (int c = 0; c < 8; c++)
                    o[c] = (short)f2bf(0.9f * acc[c] + 0.1f * bf2f((ushort_t)h[c]));
            } else {
#pragma unroll
                for (int c = 0; c < 8; c++) o[c] = 0;
            }
            *(short8*)&sS[wave * 16 + r][sl * 8] = o;
        }
    }
    __syncthreads();

    // ---- gemm phase ----
    short8 afrag[4];
#pragma unroll
    for (int ks = 0; ks < 4; ks++)
        afrag[ks] = *(const short8*)&sS[wave * 16 + l16][ks * 32 + quad * 8];

    floatx4 gacc[8];
#pragma unroll
    for (int nt = 0; nt < 8; nt++) {
        const ushort_t* bp = Wt + (size_t)(nt * 16 + l16) * HDIM + quad * 8;
        floatx4 c = (floatx4){0.f, 0.f, 0.f, 0.f};
#pragma unroll
        for (int ks = 0; ks < 4; ks++) {
            short8 b = *(const short8*)(bp + ks * 32);
            c = __builtin_amdgcn_mfma_f32_16x16x32_bf16(afrag[ks], b, c, 0, 0, 0);
        }
        gacc[nt] = c;
    }
    float g = 1.f - beta;
#pragma unroll
    for (int nt = 0; nt < 8; nt++) {
        int col = nt * 16 + l16;
#pragma unroll
        for (int r = 0; r < 4; r++) {
            int lrow = wave * 16 + quad * 4 + r;
            float s = bf2f((ushort_t)sS[lrow][col]);
            float v = beta * gacc[nt][r] + g * s;
            v = v > 0.f ? v : 0.f;
            X[(size_t)(row0 + lrow) * HDIM + col] = f2bf(v);
        }
    }
}

// ---------------- fc1: out = x @ W1 + b1 (fp32 out), N padded 40->48 ----------------

__global__ void fc1_mfma(const ushort_t* __restrict__ X, const ushort_t* __restrict__ Wt1,
                         const float* __restrict__ b1, float* __restrict__ out) {
    int wave = threadIdx.x >> 6;
    int lane = threadIdx.x & 63;
    int quad = lane >> 4, l16 = lane & 15;
    int row0 = blockIdx.x * 64 + wave * 16;

    int arow = row0 + l16; if (arow > N_NODES - 1) arow = N_NODES - 1;
    const ushort_t* ap = X + (size_t)arow * HDIM + quad * 8;
    short8 afrag[4];
#pragma unroll
    for (int ks = 0; ks < 4; ks++) afrag[ks] = *(const short8*)(ap + ks * 32);

    floatx4 acc[3];
#pragma unroll
    for (int nt = 0; nt < 3; nt++) {
        const ushort_t* bp = Wt1 + (size_t)(nt * 16 + l16) * HDIM + quad * 8;
        floatx4 c = (floatx4){0.f, 0.f, 0.f, 0.f};
#pragma unroll
        for (int ks = 0; ks < 4; ks++) {
            short8 b = *(const short8*)(bp + ks * 32);
            c = __builtin_amdgcn_mfma_f32_16x16x32_bf16(afrag[ks], b, c, 0, 0, 0);
        }
        acc[nt] = c;
    }
#pragma unroll
    for (int nt = 0; nt < 3; nt++) {
        int col = nt * 16 + l16;
        if (col < CDIM) {
            float bias = b1[col];
#pragma unroll
            for (int r = 0; r < 4; r++) {
                int row = row0 + quad * 4 + r;
                if (row < N_NODES)
                    out[(size_t)row * CDIM + col] = acc[nt][r] + bias;
            }
        }
    }
}

// ---------------- launch ----------------

extern "C" void kernel_launch(void* const* d_in, const int* in_sizes, int n_in,
                              void* d_out, int out_size, void* d_ws, size_t ws_size,
                              hipStream_t stream) {
    const float* F     = (const float*)d_in[0];
    const int*   ei    = (const int*)d_in[1];
    const float* normA = (const float*)d_in[2];
    const float* W0    = (const float*)d_in[3];
    const float* b0    = (const float*)d_in[4];
    const float* convW = (const float*)d_in[5];
    const float* W1    = (const float*)d_in[6];
    const float* b1    = (const float*)d_in[7];
    float*       out   = (float*)d_out;

    // workspace layout (bf16 trunk), 16B-aligned
    ushort_t* h0b  = (ushort_t*)d_ws;                     // M_PAD*128
    ushort_t* xab  = h0b + (size_t)M_PAD * HDIM;
    ushort_t* xbb  = xab + (size_t)M_PAD * HDIM;
    ushort_t* Wt0  = xbb + (size_t)M_PAD * HDIM;          // 128*512
    ushort_t* WtL  = Wt0 + 128 * 512;                     // 8*128*128
    ushort_t* Wt1  = WtL + 8 * 128 * 128;                 // 48*128
    int*   row_start = (int*)(Wt1 + 48 * 128);
    int*   cursor    = row_start + (N_NODES + 8);
    int*   cnt       = cursor + (N_NODES + 8);
    int*   bsum      = cnt + (N_NODES + 8);
    int*   boff      = bsum + 256;
    int2*  perm      = (int2*)(boff + 256);               // 8B-aligned

    // CSR build
    hipMemsetAsync(cnt, 0, N_NODES * sizeof(int), stream);
    hist_kernel<<<(E_EDGES + 255) / 256, 256, 0, stream>>>(ei + E_EDGES, cnt);
    scanA<<<NB, 256, 0, stream>>>(cnt, bsum);
    scanB<<<1, 256, 0, stream>>>(bsum, boff);
    scanC<<<NB, 256, 0, stream>>>(cnt, boff, row_start, cursor);
    scatter_kernel<<<(E_EDGES + 255) / 256, 256, 0, stream>>>(ei, normA, cursor, perm);
    prep_weights<<<(128 * 512 + 8 * 128 * 128 + 48 * 128 + 255) / 256, 256, 0, stream>>>(
        W0, convW, W1, Wt0, WtL, Wt1);

    fc0_mfma<<<M_PAD / 64, 512, 0, stream>>>(F, Wt0, b0, h0b, xab);

    ushort_t* ping = xab;
    ushort_t* pong = xbb;
    for (int i = 0; i < LAYERS; i++) {
        float beta = logf(0.5f / (float)(i + 1) + 1.0f);
        layer_fused<<<M_PAD / 64, 256, 0, stream>>>(
            row_start, perm, ping, h0b, WtL + (size_t)i * HDIM * HDIM, pong, beta);
        ushort_t* tmp = ping; ping = pong; pong = tmp;
    }
    // after 8 layers, result is back in xab
    fc1_mfma<<<M_PAD / 64, 256, 0, stream>>>(xab, Wt1, b1, out);
}